// Round 8
// baseline (3809.045 us; speedup 1.0000x reference)
//
#include <hip/hip_runtime.h>
#include <cstdint>
#include <cstddef>

// ---------------------------------------------------------------------------
// Problem constants
// ---------------------------------------------------------------------------
#define BB 32      // batch
#define TT 512     // seq len
#define DD 512     // emb dim
#define HH 512     // lstm size
#define DIRS 10    // 5 stacks x {fw,bw}
#define HSZ ((size_t)DIRS * BB * HH)     // elems per h ping-pong buffer
#define LWPITCH 520                      // 512 + 8 pad (16B-aligned rows, 2-way max on b128)
#define SMEM_REC (128 * LWPITCH * 2 + 2 * 2 * 4 * 4 * 64 * 4)   // 133120 + 16384 = 149504

typedef unsigned short u16;
typedef __attribute__((ext_vector_type(8))) short short8;   // 8 x bf16 (4 VGPRs)
typedef __attribute__((ext_vector_type(4))) float f32x4;    // MFMA accum

__device__ __forceinline__ u16 f2b(float f) {
    union { float f; unsigned u; } v; v.f = f;
    unsigned u = v.u;
    u = (u + 0x7FFFu + ((u >> 16) & 1u)) >> 16;   // RNE
    return (u16)u;
}
__device__ __forceinline__ float b2f(u16 b) {
    union { unsigned u; float f; } v; v.u = ((unsigned)b) << 16;
    return v.f;
}
__device__ __forceinline__ float sigm(float x) { return 1.f / (1.f + __expf(-x)); }
__device__ __forceinline__ float tanh_(float x) { return 1.f - 2.f / (1.f + __expf(2.f * x)); }
__device__ __forceinline__ f32x4 fzero() { f32x4 z = {0.f, 0.f, 0.f, 0.f}; return z; }

// Coherent 16B load (LLC, vmcnt-tracked). DISCIPLINE (round-3/4 lesson):
// results are compiler-invisible in-flight values — issue -> explicit
// s_waitcnt vmcnt(0)+sched_barrier -> consume, all inside one phase;
// never live across a __syncthreads.
// ROUND-8 rule: while these are in flight there must be NO compiler-tracked
// vmem loads outstanding, or the compiler's vmcnt(N) (counting only its own)
// over-waits and silently drains these (r7 lost the whole h RTT at ks6).
__device__ __forceinline__ uint4 load_coh16(const u16* p) {
    uint4 r;
    asm volatile("global_load_dwordx4 %0, %1, off sc0 sc1"
                 : "=v"(r) : "v"(p) : "memory");
    return r;
}

// ---------------------------------------------------------------------------
// K1: x fp32 -> bf16
// ---------------------------------------------------------------------------
__global__ void k_convx(const float* __restrict__ X, u16* __restrict__ XB) {
    int i = blockIdx.x * 256 + threadIdx.x;
    if (i >= (BB * TT * DD) / 4) return;
    float4 v = ((const float4*)X)[i];
    unsigned lo = (unsigned)f2b(v.x) | ((unsigned)f2b(v.y) << 16);
    unsigned hi = (unsigned)f2b(v.z) | ((unsigned)f2b(v.w) << 16);
    uint2 o; o.x = lo; o.y = hi;
    ((uint2*)XB)[i] = o;
}

// ---------------------------------------------------------------------------
// K2: build WT[d][n][k] = W_src[s][k][n] (bf16), LDS-tiled transpose.
// ---------------------------------------------------------------------------
__global__ void k_wt(const float* __restrict__ Wf, const float* __restrict__ Wb,
                     u16* __restrict__ WT) {
    int d = blockIdx.z, s = d >> 1;
    const float* src = (d & 1) ? Wb : Wf;   // [5][1024][2048]
    __shared__ float tile[32][33];
    int tx = threadIdx.x & 31, ty = threadIdx.x >> 5;
    int kt = blockIdx.x, nt = blockIdx.y;
#pragma unroll
    for (int r = 0; r < 4; r++) {
        int k = kt * 32 + ty + r * 8, n = nt * 32 + tx;
        tile[ty + r * 8][tx] = src[((size_t)s * 1024 + k) * 2048 + n];
    }
    __syncthreads();
#pragma unroll
    for (int r = 0; r < 4; r++) {
        int n = nt * 32 + ty + r * 8, k = kt * 32 + tx;
        WT[((size_t)d * 2048 + n) * 1024 + k] = f2b(tile[tx][ty + r * 8]);
    }
}

// ---------------------------------------------------------------------------
// K3: build head weight WBT[64 c][5120 k] bf16 + bias B64[64].
// ---------------------------------------------------------------------------
__global__ void k_wbt(const float* W1, const float* W2, const float* W3, const float* W4,
                      const float* b1, const float* b2, const float* b3, const float* b4,
                      u16* __restrict__ WBT, float* __restrict__ B64) {
    int idx = blockIdx.x * 256 + threadIdx.x;
    const int off[4] = {0, 17, 26, 51};
    const int tg[4]  = {17, 9, 25, 13};
    if (idx < 64) {
        int c = idx;
        int ti = (c < 17) ? 0 : (c < 26) ? 1 : (c < 51) ? 2 : 3;
        const float* bbp[4] = {b1, b2, b3, b4};
        B64[c] = bbp[ti][c - off[ti]];
    }
    if (idx >= 64 * 5120) return;
    int c = idx / 5120, k = idx % 5120;
    int ti = (c < 17) ? 0 : (c < 26) ? 1 : (c < 51) ? 2 : 3;
    const float* Ws[4] = {W1, W2, W3, W4};
    int tag = c - off[ti];
    float v;
    if (k < 4096) {
        int i = k >> 10, kk = k & 1023;
        v = (i == ti) ? Ws[ti][(size_t)kk * tg[ti] + tag] : 0.f;
    } else {
        int kk = k - 4096;
        v = Ws[ti][(size_t)(1024 + kk) * tg[ti] + tag];
    }
    WBT[(size_t)c * 5120 + k] = f2b(v);
}

// ---------------------------------------------------------------------------
// K5: persistent kernel — r7 protocol + ROUND-8 cross-step x pipeline:
//   - x(t+1) plain loads issue at loop BOTTOM, before barrier #2: the
//     barrier's mandatory vmcnt(0) (already paid for store drain) drains
//     them for free. At step top xraw are completed register values.
//   - step: check prefetched flag -> (fallback poll) -> issue 8 asm h
//     loads -> FULL x-GEMM with ZERO tracked loads outstanding (h RTT
//     truly hidden; r7 exposed it at ks6 via compiler vmcnt over-wait) ->
//     explicit vmcnt(0)+sched_barrier -> h-GEMM.
//   - flag prefetch fa issued right after publish (crosses no barrier),
//     own block's word substituted locally (own publish guaranteed).
//   - publish/poll protocol itself identical to r7 (proven 2998 us).
// ---------------------------------------------------------------------------
__global__ __launch_bounds__(512, 2) void k_rec(
    const u16* __restrict__ WT, const u16* __restrict__ XB,
    const float* __restrict__ bfw, const float* __restrict__ bbw,
    u16* __restrict__ Hbuf, u16* __restrict__ OUTS,
    const int* __restrict__ lens, unsigned* __restrict__ flg)
{
    extern __shared__ char smem[];
    u16* lWx = (u16*)smem;                             // [128][LWPITCH] bf16
    float* red = (float*)(smem + 128 * LWPITCH * 2);   // [2][2][4][4][64]

    int blk = blockIdx.x, d = blk >> 4, jj = blk & 15;
    int s = d >> 1, isbw = d & 1;
    int tid = threadIdx.x, w = tid >> 6, lane = tid & 63, quad = lane >> 4, l15 = lane & 15;
    int mtile = w & 1, nhalf = (w >> 1) & 1, khalf = w >> 2;

    // ---- stage W_x slice into LDS (once) ----
#pragma unroll
    for (int it = 0; it < 16; ++it) {
        int g16 = it * 512 + tid;          // 8192 granules of 16B
        int row = g16 >> 6, c = g16 & 63;
        int n = (row >> 5) * 512 + jj * 32 + (row & 31);
        const u16* src = WT + ((size_t)d * 2048 + n) * 1024 + c * 8;   // x half: k in [0,512)
        *(uint4*)(lWx + row * LWPITCH + c * 8) = *(const uint4*)src;
    }

    // ---- W_h fragments: persistent registers/AGPRs ----
    short8 Bf[8][4];
#pragma unroll
    for (int ks = 0; ks < 8; ks++) {
        int k0 = khalf * 256 + ks * 32;
#pragma unroll
        for (int g = 0; g < 4; g++) {
            int n = g * 512 + jj * 32 + nhalf * 16 + l15;
            Bf[ks][g] = *(const short8*)(WT + ((size_t)d * 2048 + n) * 1024 + 512 + k0 + quad * 8);
        }
    }

    // ---- per-lane persistent state ----
    int bA = mtile * 16 + l15;             // A-fragment row (batch index)
    int lbA = lens[bA];
    int ug = jj * 32 + nhalf * 16 + l15;   // global unit index (epilogue lanes)
    const float* bias = (isbw ? bbw : bfw) + (size_t)s * 2048;
    float c_reg[4], hprev[4], bv_r[4];
    int lb_r[4];
    if (khalf == 0) {
#pragma unroll
        for (int g = 0; g < 4; g++) bv_r[g] = bias[g * 512 + ug];
#pragma unroll
        for (int r = 0; r < 4; r++) {
            int b = mtile * 16 + quad * 4 + r;
            lb_r[r] = lens[b];
            c_reg[r] = 0.f;
            hprev[r] = 0.f;
        }
    }
    const unsigned* fline = flg + d * 16;

    // ---- prologue x(0) loads: issued BEFORE the staging barrier so its
    //      vmcnt(0) drains them (free flight) ----
    uint4 xraw[8];
    {
        int srcT0 = isbw ? (lbA - 1) : 0;      // lens >= 16 so lbA-1 >= 0
        const u16* xr = XB + ((size_t)bA * TT + srcT0) * DD + khalf * 256;
#pragma unroll
        for (int ks = 0; ks < 8; ks++)
            xraw[ks] = *(const uint4*)(xr + ks * 32 + quad * 8);
    }
    unsigned fa = 0;                            // t=0 target 0: passes

    __syncthreads();   // lWx ready + x(0) drained

    for (int t = 0; t < TT; ++t) {
        unsigned tgt = (unsigned)t;

        // ---- check prefetched flag; fallback narrow poll (r7 shape) ----
        if (!__all((int)(fa >= tgt))) {
            unsigned f = tgt;
            if (lane < 16)
                f = __hip_atomic_load(fline + lane, __ATOMIC_RELAXED,
                                      __HIP_MEMORY_SCOPE_AGENT);
            if (lane == jj) f = 0xFFFFFFFFu;    // own publish guaranteed
            int spin = 0;
            while (!__all((int)(f >= tgt)) && spin < (1 << 22)) {
                __builtin_amdgcn_s_sleep(1);
                f = tgt;
                if (lane < 16)
                    f = __hip_atomic_load(fline + lane, __ATOMIC_RELAXED,
                                          __HIP_MEMORY_SCOPE_AGENT);
                if (lane == jj) f = 0xFFFFFFFFu;
                ++spin;
            }
        }

        // ---- h loads (coh asm): issue all 8; NOTHING tracked is in
        //      flight, so they stay outstanding through the x-GEMM ----
        const u16* hin = Hbuf + (size_t)(t & 1) * HSZ + (size_t)d * BB * HH;
        uint4 araw[8];
#pragma unroll
        for (int ks = 0; ks < 8; ks++)
            araw[ks] = load_coh16(hin + (size_t)bA * HH + khalf * 256 + ks * 32 + quad * 8);

        f32x4 acc[4];
#pragma unroll
        for (int g = 0; g < 4; g++) acc[g] = fzero();

        // ---- FULL x-GEMM from registers/LDS: hides the h-load RTT ----
#pragma unroll
        for (int ks = 0; ks < 8; ks++) {
            short8 a = *(const short8*)(&xraw[ks]);
#pragma unroll
            for (int g = 0; g < 4; g++) {
                short8 bfr = *(const short8*)(lWx + (g * 32 + nhalf * 16 + l15) * LWPITCH
                                              + khalf * 256 + ks * 32 + quad * 8);
                acc[g] = __builtin_amdgcn_mfma_f32_16x16x32_bf16(a, bfr, acc[g], 0, 0, 0);
            }
        }

        // drain asm h loads, then h-GEMM (rule #18 fence)
        asm volatile("s_waitcnt vmcnt(0)" ::: "memory");
        __builtin_amdgcn_sched_barrier(0);
#pragma unroll
        for (int ks = 0; ks < 8; ks++) {
            short8 a = *(const short8*)(&araw[ks]);
#pragma unroll
            for (int g = 0; g < 4; g++)
                acc[g] = __builtin_amdgcn_mfma_f32_16x16x32_bf16(a, Bf[ks][g], acc[g], 0, 0, 0);
        }

        // ---- khalf exchange through LDS ----
        if (khalf == 1) {
#pragma unroll
            for (int g = 0; g < 4; g++)
#pragma unroll
                for (int r = 0; r < 4; r++)
                    red[((((size_t)mtile * 2 + nhalf) * 4 + g) * 4 + r) * 64 + lane] = acc[g][r];
        }
        __syncthreads();   // barrier #1: red ready
        if (khalf == 0) {
#pragma unroll
            for (int g = 0; g < 4; g++)
#pragma unroll
                for (int r = 0; r < 4; r++)
                    acc[g][r] += red[((((size_t)mtile * 2 + nhalf) * 4 + g) * 4 + r) * 64 + lane];

            u16* hout = Hbuf + (size_t)((t + 1) & 1) * HSZ + (size_t)d * BB * HH;
#pragma unroll
            for (int r = 0; r < 4; r++) {
                int b = mtile * 16 + quad * 4 + r;
                int lb = lb_r[r];
                float zi = acc[0][r] + bv_r[0];
                float zj = acc[1][r] + bv_r[1];
                float zf = acc[2][r] + bv_r[2];
                float zo = acc[3][r] + bv_r[3];
                float cn = sigm(zf + 1.f) * c_reg[r] + sigm(zi) * tanh_(zj);
                float hn = sigm(zo) * tanh_(cn);
                bool act = t < lb;
                if (act) c_reg[r] = cn;
                u16 hv = f2b(act ? hn : hprev[r]);
                hprev[r] = b2f(hv);
                __hip_atomic_store(&hout[(size_t)b * HH + ug], hv,
                                   __ATOMIC_RELAXED, __HIP_MEMORY_SCOPE_AGENT);
                int twr = isbw ? (act ? (lb - 1 - t) : t) : t;   // fused reverse scatter
                OUTS[(((size_t)s * BB + b) * TT + twr) * 1024 + isbw * 512 + ug] = f2b(act ? hn : 0.f);
            }
        }

        // ---- x(t+1) loads: issued BEFORE barrier #2 so its vmcnt(0)
        //      (already paid for store drain) drains them for free ----
        {
            int tn = (t + 1 < TT) ? (t + 1) : (TT - 1);      // clamp: dead on last iter
            int srcTn = isbw ? ((tn < lbA) ? (lbA - 1 - tn) : tn) : tn;
            const u16* xrn = XB + ((size_t)bA * TT + srcTn) * DD + khalf * 256;
#pragma unroll
            for (int ks = 0; ks < 8; ks++)
                xraw[ks] = *(const uint4*)(xrn + ks * 32 + quad * 8);
        }

        __syncthreads();   // barrier #2: drains h/OUTS stores + x(t+1) loads,
                           // doubles as red-protect for next iteration
        if (tid == 0)
            __hip_atomic_store(flg + d * 16 + jj, (unsigned)(t + 1),
                               __ATOMIC_RELAXED, __HIP_MEMORY_SCOPE_AGENT);

        // ---- flag prefetch for step t+1 (crosses no barrier) ----
        fa = 0xFFFFFFFFu;
        if (lane < 16)
            fa = __hip_atomic_load(fline + lane, __ATOMIC_RELAXED,
                                   __HIP_MEMORY_SCOPE_AGENT);
        if (lane == jj) fa = 0xFFFFFFFFu;       // own publish guaranteed
    }
}

// ---------------------------------------------------------------------------
// K6: heads. logits[16384, 64] = U[16384, 5120] @ WBT^T + B64.
// ---------------------------------------------------------------------------
__global__ __launch_bounds__(256) void k_head(
    const u16* __restrict__ OUTS, const u16* __restrict__ WBT,
    const float* __restrict__ B64, float* __restrict__ OUT)
{
    int tid = threadIdx.x, w = tid >> 6, lane = tid & 63, quad = lane >> 4, l15 = lane & 15;
    int mtile = blockIdx.x * 4 + w, r0 = mtile * 16;
    int row_a = r0 + l15, ba = row_a >> 9, ta = row_a & 511;
    f32x4 acc[4];
#pragma unroll
    for (int ni = 0; ni < 4; ni++) acc[ni] = fzero();

    for (int k0 = 0; k0 < 5120; k0 += 32) {
        int kidx = k0 + quad * 8;
        int blkk = kidx >> 10, kk = kidx & 1023;
        short8 a = *(const short8*)(OUTS + (((size_t)blkk * BB + ba) * TT + ta) * 1024 + kk);
#pragma unroll
        for (int ni = 0; ni < 4; ni++) {
            short8 bf = *(const short8*)(WBT + (size_t)(ni * 16 + l15) * 5120 + kidx);
            acc[ni] = __builtin_amdgcn_mfma_f32_16x16x32_bf16(a, bf, acc[ni], 0, 0, 0);
        }
    }
#pragma unroll
    for (int ni = 0; ni < 4; ni++) {
        int c = ni * 16 + l15;
        float bv = B64[c];
#pragma unroll
        for (int r = 0; r < 4; r++) {
            int row = r0 + quad * 4 + r;
            OUT[(size_t)row * 64 + c] = acc[ni][r] + bv;
        }
    }
}

// ---------------------------------------------------------------------------
extern "C" void kernel_launch(void* const* d_in, const int* in_sizes, int n_in,
                              void* d_out, int out_size, void* d_ws, size_t ws_size,
                              hipStream_t stream) {
    const float* X   = (const float*)d_in[0];
    const int* lens  = (const int*)d_in[1];
    const float* Wf  = (const float*)d_in[2];
    const float* bf_ = (const float*)d_in[3];
    const float* Wb  = (const float*)d_in[4];
    const float* bb_ = (const float*)d_in[5];
    const float* W1  = (const float*)d_in[6];
    const float* b1  = (const float*)d_in[7];
    const float* W2  = (const float*)d_in[8];
    const float* b2  = (const float*)d_in[9];
    const float* W3  = (const float*)d_in[10];
    const float* b3  = (const float*)d_in[11];
    const float* W4  = (const float*)d_in[12];
    const float* b4  = (const float*)d_in[13];

    // ---- runtime workspace layout ----
    char* ws = (char*)d_ws;
    size_t off = 0;
    auto take = [&](size_t bytes) { size_t o = off; off += (bytes + 255) & ~(size_t)255; return o; };
    size_t wtOff   = take((size_t)DIRS * 2048 * 1024 * 2);
    size_t xbOff   = take((size_t)BB * TT * DD * 2);
    size_t outsOff = take((size_t)5 * BB * TT * 1024 * 2);
    size_t hOff    = take((size_t)2 * HSZ * 2);
    size_t flgOff  = take((size_t)DIRS * 16 * 4);      // 16 flag words (64B line) per dir
    size_t wbtOff  = take((size_t)64 * 5120 * 2);
    size_t b64Off  = take((size_t)64 * 4);

    u16* WT    = (u16*)(ws + wtOff);
    u16* XB    = (u16*)(ws + xbOff);
    u16* OUTS  = (u16*)(ws + outsOff);
    u16* Hbuf  = (u16*)(ws + hOff);
    unsigned* FLG = (unsigned*)(ws + flgOff);
    u16* WBT   = (u16*)(ws + wbtOff);
    float* B64 = (float*)(ws + b64Off);

    // zero the ENTIRE [H | FLG] span every launch (flags MUST reset; h(0)=0)
    hipMemsetAsync(ws + hOff, 0, wbtOff - hOff, stream);

    // 149.5 KB dynamic LDS for the persistent kernel
    (void)hipFuncSetAttribute((const void*)k_rec,
                              hipFuncAttributeMaxDynamicSharedMemorySize, SMEM_REC);

    k_convx<<<8192, 256, 0, stream>>>(X, XB);
    k_wt<<<dim3(32, 64, 10), 256, 0, stream>>>(Wf, Wb, WT);
    k_wbt<<<1280, 256, 0, stream>>>(W1, W2, W3, W4, b1, b2, b3, b4, WBT, B64);

    // one persistent dispatch for all 512 timesteps
    k_rec<<<160, 512, SMEM_REC, stream>>>(WT, XB, bf_, bb_, Hbuf, OUTS, lens, FLG);

    k_head<<<256, 256, 0, stream>>>(OUTS, WBT, B64, (float*)d_out);
}